// Round 7
// baseline (321.859 us; speedup 1.0000x reference)
//
#include <hip/hip_runtime.h>

#define B_    16
#define D_    256
#define H_    32
#define W_    32
#define SP    1024        // H_*W_
#define N_TOT 16384       // B_*SP
#define K_    8192
#define ZB    (D_*SP)     // floats per batch in z

#define BIAS_  0.03125f
#define DELTA_ 2.5e-4f

typedef __attribute__((ext_vector_type(8))) short bf16x8;
typedef __attribute__((ext_vector_type(4))) short bf16x4;
typedef __attribute__((ext_vector_type(4))) float f32x4;

__device__ __forceinline__ unsigned short f2bf(float f) {
    unsigned u = __float_as_uint(f);
    u += 0x7FFFu + ((u >> 16) & 1u);          // RNE
    return (unsigned short)(u >> 16);
}

// merge two sorted pairs (a1<=a2), (b1<=b2) -> top-2 in (a1,a2). u32 lex keys.
__device__ __forceinline__ void merge2(unsigned &a1, unsigned &a2,
                                       unsigned b1, unsigned b2) {
    unsigned m1  = min(a1, b1);
    unsigned hi  = max(a1, b1);
    unsigned sel = (a1 < b1) ? a2 : b2;
    a2 = min(hi, sel);
    a1 = m1;
}

// ================= fused prep: e-convert+enorm  |  z-convert+zpart =================
// blocks [0,2048): per-code enorm (tree IDENTICAL to r1-6) + tiled-swizzled ET3
// blocks [2048,2304): zpart chunks (IDENTICAL 16x16 trees) + tiled-swizzled ZT3

__global__ __launch_bounds__(256)
void prep_kernel(const float* __restrict__ emb, const float* __restrict__ z,
                 short* __restrict__ ET3, short* __restrict__ ZT3,
                 float* __restrict__ zpart, float* __restrict__ enorm,
                 float* __restrict__ enormB, int* __restrict__ wl_cnt) {
    const int bx = blockIdx.x;
    const int t  = threadIdx.x;
    if (bx < 2048) {
        int k = bx * 4 + (t >> 6);
        int l = t & 63;
        float4 v = *(const float4*)(emb + (size_t)k * D_ + l * 4);
        float sum = v.x*v.x + v.y*v.y + v.z*v.z + v.w*v.w;
        for (int m = 1; m < 64; m <<= 1) sum += __shfl_xor(sum, m, 64);
        if (l == 0) { enorm[k] = sum; enormB[k] = sum + BIAS_; }
        int dcb  = l >> 4;
        int c    = (l >> 1) & 7;
        int half = l & 1;
        bf16x4 o;
        o[0] = (short)f2bf(v.x); o[1] = (short)f2bf(v.y);
        o[2] = (short)f2bf(v.z); o[3] = (short)f2bf(v.w);
        *(bf16x4*)(ET3 + ((size_t)dcb * K_ + k) * 64 + ((c ^ (k & 7)) * 8) + half * 4) = o;
    } else {
        int bz  = bx - 2048;
        if (bz == 0 && t == 0) *wl_cnt = 0;
        int dcb = bz >> 6;
        int st  = bz & 63;
        int n   = st * 256 + t;
        int b   = n >> 10;
        int s   = n & 1023;
        const float* zb = z + (size_t)b * ZB + (size_t)(dcb * 64) * SP + s;
        short* dst = ZT3 + ((size_t)dcb * N_TOT + n) * 64;
        int sw = n & 7;
#pragma unroll
        for (int c2 = 0; c2 < 4; ++c2) {
            float vv[16];
#pragma unroll
            for (int dd = 0; dd < 16; ++dd)
                vv[dd] = zb[(size_t)(c2 * 16 + dd) * SP];
            float sum = 0.f;
#pragma unroll
            for (int dd = 0; dd < 16; ++dd) {
                float v = vv[dd];
                sum += v * v;
            }
            zpart[(size_t)(dcb * 4 + c2) * N_TOT + n] = sum;
            bf16x8 o0, o1;
#pragma unroll
            for (int j = 0; j < 8; ++j) { o0[j] = (short)f2bf(vv[j]);
                                          o1[j] = (short)f2bf(vv[8 + j]); }
            *(bf16x8*)(dst + (((c2 * 2)     ^ sw) * 8)) = o0;
            *(bf16x8*)(dst + (((c2 * 2 + 1) ^ sw) * 8)) = o1;
        }
    }
}

// ============== MFMA GEMM + packed-key top-2, reg-staged double-buffer ==============
// argmin2's exact tiles/layout/epilogue; staging = buffer_load->VGPR->ds_write into
// alternating 32KB LDS halves. Per stage: write(s); barrier (vmcnt already 0 — the
// ds_write consumed the loads); prefetch(s+1); compute(s). Load latency hides under
// the 32 MFMAs of compute(s).

__global__ __launch_bounds__(256, 2)
void mfma_argmin4(const short* __restrict__ ET3, const short* __restrict__ ZT3,
                  const float* __restrict__ enormB, uint2* __restrict__ pv) {
    __shared__ char smem[65536];               // 2 x (A 16KB | B 16KB)
    const int t    = threadIdx.x;
    const int wid  = t >> 6, lane = t & 63;
    const int quad = lane >> 4, l16 = lane & 15;
    const int wm   = wid >> 1, wn = wid & 1;
    const int stripe = blockIdx.x >> 7;
    const int n0     = (blockIdx.x & 127) * 128;
    const int swz    = (l16 & 7);

    unsigned r1[4], r2[4];
#pragma unroll
    for (int fj = 0; fj < 4; ++fj) { r1[fj] = 0xFFFFFFFFu; r2[fj] = 0xFFFFFFFFu; }

    int4 ra[4], rb[4];
    {   // preload stage (cc=0, dcb=0)
        const char* gA = (const char*)ET3 + ((size_t)stripe * 1024) * 128;
        const char* gB = (const char*)ZT3 + ((size_t)n0) * 128;
#pragma unroll
        for (int j = 0; j < 4; ++j) {
            ra[j] = *(const int4*)(gA + j * 4096 + t * 16);
            rb[j] = *(const int4*)(gB + j * 4096 + t * 16);
        }
    }

#pragma unroll 1
    for (int cc = 0; cc < 8; ++cc) {
        const int c0 = stripe * 1024 + cc * 128;
        f32x4 acc[4][4];
#pragma unroll
        for (int fi = 0; fi < 4; ++fi)
#pragma unroll
            for (int fj = 0; fj < 4; ++fj) acc[fi][fj] = (f32x4){0.f, 0.f, 0.f, 0.f};

#pragma unroll
        for (int dcb = 0; dcb < 4; ++dcb) {
            char* bufA = smem + (dcb & 1) * 32768;
            char* bufB = bufA + 16384;
#pragma unroll
            for (int j = 0; j < 4; ++j) {      // ds_write consumes the loads
                *(int4*)(bufA + j * 4096 + t * 16) = ra[j];
                *(int4*)(bufB + j * 4096 + t * 16) = rb[j];
            }
            __syncthreads();                   // vmcnt already drained -> cheap
            if (dcb < 3) {                     // prefetch (cc, dcb+1)
                const char* gA = (const char*)ET3 + ((size_t)(dcb + 1) * K_ + c0) * 128;
                const char* gB = (const char*)ZT3 + ((size_t)(dcb + 1) * N_TOT + n0) * 128;
#pragma unroll
                for (int j = 0; j < 4; ++j) {
                    ra[j] = *(const int4*)(gA + j * 4096 + t * 16);
                    rb[j] = *(const int4*)(gB + j * 4096 + t * 16);
                }
            } else if (cc < 7) {               // prefetch (cc+1, 0)
                const char* gA = (const char*)ET3 + ((size_t)(c0 + 128)) * 128;
                const char* gB = (const char*)ZT3 + ((size_t)n0) * 128;
#pragma unroll
                for (int j = 0; j < 4; ++j) {
                    ra[j] = *(const int4*)(gA + j * 4096 + t * 16);
                    rb[j] = *(const int4*)(gB + j * 4096 + t * 16);
                }
            }
#pragma unroll
            for (int dc2 = 0; dc2 < 2; ++dc2) {
                bf16x8 af[4], bfv[4];
                const int chm = ((dc2 * 4 + quad) ^ swz) * 16;
#pragma unroll
                for (int fi = 0; fi < 4; ++fi)
                    af[fi] = *(const bf16x8*)(bufA + (wm*64 + fi*16 + l16)*128 + chm);
#pragma unroll
                for (int fj = 0; fj < 4; ++fj)
                    bfv[fj] = *(const bf16x8*)(bufB + (wn*64 + fj*16 + l16)*128 + chm);
#pragma unroll
                for (int fi = 0; fi < 4; ++fi)
#pragma unroll
                    for (int fj = 0; fj < 4; ++fj)
                        acc[fi][fj] = __builtin_amdgcn_mfma_f32_16x16x32_bf16(
                            af[fi], bfv[fj], acc[fi][fj], 0, 0, 0);
            }
        }

        // epilogue (identical arithmetic to proven rounds 3-6)
        float ekv[4][4];
#pragma unroll
        for (int fi = 0; fi < 4; ++fi) {
            float4 e4 = *(const float4*)(enormB + c0 + wm*64 + fi*16 + quad*4);
            ekv[fi][0]=e4.x; ekv[fi][1]=e4.y; ekv[fi][2]=e4.z; ekv[fi][3]=e4.w;
        }
#pragma unroll
        for (int fj = 0; fj < 4; ++fj) {
#pragma unroll
            for (int fi = 0; fi < 4; ++fi) {
                const unsigned cb = (unsigned)(c0 + wm*64 + fi*16 + quad*4);
                float s0 = fmaf(-2.f, acc[fi][fj].x, ekv[fi][0]);
                float s1 = fmaf(-2.f, acc[fi][fj].y, ekv[fi][1]);
                float s2 = fmaf(-2.f, acc[fi][fj].z, ekv[fi][2]);
                float s3 = fmaf(-2.f, acc[fi][fj].w, ekv[fi][3]);
                unsigned k0 = (__float_as_uint(s0) & 0xFFFFE000u) | (cb + 0u);
                unsigned k1 = (__float_as_uint(s1) & 0xFFFFE000u) | (cb + 1u);
                unsigned k2 = (__float_as_uint(s2) & 0xFFFFE000u) | (cb + 2u);
                unsigned k3 = (__float_as_uint(s3) & 0xFFFFE000u) | (cb + 3u);
                unsigned lo1 = min(k0, k1), hi1 = max(k0, k1);
                unsigned lo2 = min(k2, k3), hi2 = max(k2, k3);
                merge2(lo1, hi1, lo2, hi2);
                merge2(r1[fj], r2[fj], lo1, hi1);
            }
        }
    }

#pragma unroll
    for (int fj = 0; fj < 4; ++fj) {
        unsigned a1 = r1[fj], a2 = r2[fj];
#pragma unroll
        for (int m = 16; m <= 32; m <<= 1) {
            unsigned b1 = __shfl_xor(a1, m, 64);
            unsigned b2 = __shfl_xor(a2, m, 64);
            merge2(a1, a2, b1, b2);
        }
        if (quad == 0) {
            int n = n0 + wn*64 + fj*16 + l16;
            pv[(size_t)(stripe * 2 + wm) * N_TOT + n] = make_uint2(a1, a2);
        }
    }
}

// ============== phase A: znorm (ordered sum, identical) + window classify ==============

template <int NG>
__global__ __launch_bounds__(256)
void phaseA_z(const uint2* __restrict__ pv, const float* __restrict__ zpart,
              float* __restrict__ znorm, int* __restrict__ fidx,
              float* __restrict__ out_idx, int* __restrict__ wl,
              int* __restrict__ wl_cnt, float* __restrict__ out_loss) {
    int n = blockIdx.x * 256 + threadIdx.x;
    if (n == 0) *out_loss = 0.f;
    float zsum = 0.f;
#pragma unroll
    for (int dc = 0; dc < 16; ++dc) zsum += zpart[(size_t)dc * N_TOT + n];
    znorm[n] = zsum;
    uint2 pp[NG];
    unsigned mn = 0xFFFFFFFFu;
#pragma unroll
    for (int g = 0; g < NG; ++g) {
        pp[g] = pv[(size_t)g * N_TOT + n];
        mn = min(mn, pp[g].x);
    }
    float smin  = __uint_as_float(mn & 0xFFFFE000u);
    unsigned th = __float_as_uint(smin + DELTA_) | 8191u;
    int cnt = 0;
#pragma unroll
    for (int g = 0; g < NG; ++g) {
        cnt += (pp[g].x <= th) ? 1 : 0;
        cnt += (pp[g].y <= th) ? 1 : 0;
    }
    if (cnt > 1) {
        int slot = atomicAdd(wl_cnt, 1);
        wl[slot] = n;
    } else {
        int c = (int)(mn & 8191u);
        fidx[n] = c;
        out_idx[n] = (float)c;
    }
}

// ============== phase B: one wave per recheck row (exact chain, unchanged) ==============

template <int NG>
__global__ __launch_bounds__(256)
void recheck_t(const uint2* __restrict__ pv, const float* __restrict__ znorm,
               const float* __restrict__ enorm, const float* __restrict__ z,
               const float* __restrict__ emb, const int* __restrict__ wl,
               const int* __restrict__ wl_cnt, int* __restrict__ fidx,
               float* __restrict__ out_idx) {
    __shared__ float zrow[4][256];
    const int lane = threadIdx.x & 63;
    const int wslot = threadIdx.x >> 6;
    const int gwave = (blockIdx.x * 256 + threadIdx.x) >> 6;
    const int nwaves = (gridDim.x * 256) >> 6;
    const int total = *wl_cnt;

    for (int i = gwave; i < total; i += nwaves) {
        int n = wl[i];
        unsigned key = 0xFFFFFFFFu;
        if (lane < 2 * NG) {
            uint2 p = pv[(size_t)(lane >> 1) * N_TOT + n];
            key = (lane & 1) ? p.y : p.x;
        }
        unsigned mn = key;
#pragma unroll
        for (int m = 1; m < 64; m <<= 1) mn = min(mn, __shfl_xor(mn, m, 64));
        float smin  = __uint_as_float(mn & 0xFFFFE000u);
        unsigned th = __float_as_uint(smin + DELTA_) | 8191u;

        const int b = n >> 10, sp = n & 1023;
        const float* zr = z + (size_t)b * ZB + sp;
#pragma unroll
        for (int j = 0; j < 4; ++j)
            zrow[wslot][lane + j * 64] = zr[(size_t)(lane + j * 64) * SP];
        float zn = znorm[n];

        unsigned lexlo = 0xFFFFFFFFu, lexhi = 0xFFFFFFFFu;
        if (key <= th) {
            int c = (int)(key & 8191u);
            const float* er = emb + (size_t)c * D_;
            float dot = 0.f;
#pragma unroll 8
            for (int d = 0; d < D_; ++d)
                dot = fmaf(zrow[wslot][d], er[d], dot);
            float s = (zn + enorm[c]) - 2.f * dot;
            unsigned sb = __float_as_uint(s);
            lexhi = sb >> 19;
            lexlo = (sb << 13) | (unsigned)c;
        }
#pragma unroll
        for (int m = 1; m < 64; m <<= 1) {
            unsigned olo = __shfl_xor(lexlo, m, 64);
            unsigned ohi = __shfl_xor(lexhi, m, 64);
            if (ohi < lexhi || (ohi == lexhi && olo < lexlo)) { lexhi = ohi; lexlo = olo; }
        }
        if (lane == 0) {
            int c = (int)(lexlo & 8191u);
            fidx[n] = c;
            out_idx[n] = (float)c;
        }
    }
}

// ======================= output / loss (unchanged) =======================

__global__ __launch_bounds__(256)
void output_kernel2(const float* __restrict__ z, const float* __restrict__ emb,
                    const int* __restrict__ fidx, float* __restrict__ out,
                    float* __restrict__ loss) {
    __shared__ float eL[32][257];
    __shared__ int   fid[32];
    __shared__ float red[4];
    const int nb = blockIdx.x;
    const int n0 = nb * 32;
    const int b  = n0 >> 10;
    const int s0 = n0 & 1023;
    const int t  = threadIdx.x;
    if (t < 32) fid[t] = fidx[n0 + t];
    __syncthreads();
#pragma unroll
    for (int i = 0; i < 8; ++i) {
        int p = t + i * 256;
        int row = p >> 6, q = p & 63;
        float4 v = *(const float4*)(emb + (size_t)fid[row] * D_ + q * 4);
        eL[row][q*4+0] = v.x; eL[row][q*4+1] = v.y;
        eL[row][q*4+2] = v.z; eL[row][q*4+3] = v.w;
    }
    __syncthreads();
    const int sl = t & 31, dg = t >> 5;
    float lsum = 0.f;
#pragma unroll
    for (int i = 0; i < 32; ++i) {
        int d = dg * 32 + i;
        size_t off = ((size_t)(b * D_ + d)) * SP + s0 + sl;
        float zv = z[off];
        float q  = eL[sl][d];
        float diff = q - zv;
        out[off] = zv + diff;
        lsum += diff * diff;
    }
    for (int m = 1; m < 64; m <<= 1) lsum += __shfl_xor(lsum, m, 64);
    if ((t & 63) == 0) red[t >> 6] = lsum;
    __syncthreads();
    if (t == 0) {
        float tot = (red[0] + red[1] + red[2] + red[3])
                    * (1.25f / (float)(B_ * SP * D_));
        atomicAdd(loss, tot);
    }
}

// ======================= launch =======================
// ws layout (floats) — NEED = 15,991,296 B (ws >= 17,039,872 proven in round 6):
//   enorm [0,8192) enormB [8192,16384) znorm [16384,32768) fidx [32768,49152)
//   wl_cnt 49152 (pad 49216) wl [49216,65600) (pad 65664)
//   zpart [65664,327808)   pv16 [327808,852096)
//   ET3 (short) [852096,1900672)   ZT3 (short) [1900672,3997824)

extern "C" void kernel_launch(void* const* d_in, const int* in_sizes, int n_in,
                              void* d_out, int out_size, void* d_ws, size_t ws_size,
                              hipStream_t stream) {
    const float* z   = (const float*)d_in[0];
    const float* emb = (const float*)d_in[1];
    float* out = (float*)d_out;
    float* w   = (float*)d_ws;

    float* enorm  = w;
    float* enormB = w + 8192;
    float* znorm  = w + 16384;
    int*   fidx   = (int*)(w + 32768);
    int*   wl_cnt = (int*)(w + 49152);
    int*   wl     = (int*)(w + 49216);
    float* zpart  = w + 65664;
    uint2* pv     = (uint2*)(w + 327808);
    short* ET3    = (short*)(w + 852096);
    short* ZT3    = (short*)(w + 1900672);

    float* out0     = out;
    float* out_loss = out + (size_t)B_ * D_ * SP;
    float* out_idx  = out_loss + 1;

    prep_kernel<<<2304, 256, 0, stream>>>(emb, z, ET3, ZT3, zpart,
                                          enorm, enormB, wl_cnt);
    mfma_argmin4<<<1024, 256, 0, stream>>>(ET3, ZT3, enormB, pv);
    phaseA_z<16><<<N_TOT / 256, 256, 0, stream>>>(pv, zpart, znorm, fidx,
                                                  out_idx, wl, wl_cnt, out_loss);
    recheck_t<16><<<256, 256, 0, stream>>>(pv, znorm, enorm, z, emb,
                                           wl, wl_cnt, fidx, out_idx);
    output_kernel2<<<N_TOT / 32, 256, 0, stream>>>(z, emb, fidx, out0, out_loss);
}

// Round 8
// 234.810 us; speedup vs baseline: 1.3707x; 1.3707x over previous
//
#include <hip/hip_runtime.h>

#define B_    16
#define D_    256
#define H_    32
#define W_    32
#define SP    1024        // H_*W_
#define N_TOT 16384       // B_*SP
#define K_    8192
#define ZB    (D_*SP)     // floats per batch in z

#define BIAS_  0.03125f
#define DELTA_ 2.5e-4f

typedef __attribute__((ext_vector_type(8))) short bf16x8;
typedef __attribute__((ext_vector_type(4))) short bf16x4;
typedef __attribute__((ext_vector_type(4))) float f32x4;

#define GLOAD_LDS16(g, l) \
    __builtin_amdgcn_global_load_lds((const __attribute__((address_space(1))) void*)(g), \
                                     (__attribute__((address_space(3))) void*)(l), 16, 0, 0)

__device__ __forceinline__ unsigned short f2bf(float f) {
    unsigned u = __float_as_uint(f);
    u += 0x7FFFu + ((u >> 16) & 1u);          // RNE
    return (unsigned short)(u >> 16);
}

// merge two sorted pairs (a1<=a2), (b1<=b2) -> top-2 in (a1,a2). u32 lex keys.
__device__ __forceinline__ void merge2(unsigned &a1, unsigned &a2,
                                       unsigned b1, unsigned b2) {
    unsigned m1  = min(a1, b1);
    unsigned hi  = max(a1, b1);
    unsigned sel = (a1 < b1) ? a2 : b2;
    a2 = min(hi, sel);
    a1 = m1;
}

// ================= fused prep: e-convert+enorm  |  z-convert+zpart =================
// blocks [0,2048): per-code enorm (tree IDENTICAL to r1-7) + tiled-swizzled ET3
// blocks [2048,2304): zpart chunks (IDENTICAL 16x16 trees) + tiled-swizzled ZT3

__global__ __launch_bounds__(256)
void prep_kernel(const float* __restrict__ emb, const float* __restrict__ z,
                 short* __restrict__ ET3, short* __restrict__ ZT3,
                 float* __restrict__ zpart, float* __restrict__ enorm,
                 float* __restrict__ enormB, int* __restrict__ wl_cnt) {
    const int bx = blockIdx.x;
    const int t  = threadIdx.x;
    if (bx < 2048) {
        int k = bx * 4 + (t >> 6);
        int l = t & 63;
        float4 v = *(const float4*)(emb + (size_t)k * D_ + l * 4);
        float sum = v.x*v.x + v.y*v.y + v.z*v.z + v.w*v.w;
        for (int m = 1; m < 64; m <<= 1) sum += __shfl_xor(sum, m, 64);
        if (l == 0) { enorm[k] = sum; enormB[k] = sum + BIAS_; }
        int dcb  = l >> 4;
        int c    = (l >> 1) & 7;
        int half = l & 1;
        bf16x4 o;
        o[0] = (short)f2bf(v.x); o[1] = (short)f2bf(v.y);
        o[2] = (short)f2bf(v.z); o[3] = (short)f2bf(v.w);
        *(bf16x4*)(ET3 + ((size_t)dcb * K_ + k) * 64 + ((c ^ (k & 7)) * 8) + half * 4) = o;
    } else {
        int bz  = bx - 2048;
        if (bz == 0 && t == 0) *wl_cnt = 0;
        int dcb = bz >> 6;
        int st  = bz & 63;
        int n   = st * 256 + t;
        int b   = n >> 10;
        int s   = n & 1023;
        const float* zb = z + (size_t)b * ZB + (size_t)(dcb * 64) * SP + s;
        short* dst = ZT3 + ((size_t)dcb * N_TOT + n) * 64;
        int sw = n & 7;
#pragma unroll
        for (int c2 = 0; c2 < 4; ++c2) {
            float vv[16];
#pragma unroll
            for (int dd = 0; dd < 16; ++dd)
                vv[dd] = zb[(size_t)(c2 * 16 + dd) * SP];
            float sum = 0.f;
#pragma unroll
            for (int dd = 0; dd < 16; ++dd) {
                float v = vv[dd];
                sum += v * v;
            }
            zpart[(size_t)(dcb * 4 + c2) * N_TOT + n] = sum;
            bf16x8 o0, o1;
#pragma unroll
            for (int j = 0; j < 8; ++j) { o0[j] = (short)f2bf(vv[j]);
                                          o1[j] = (short)f2bf(vv[8 + j]); }
            *(bf16x8*)(dst + (((c2 * 2)     ^ sw) * 8)) = o0;
            *(bf16x8*)(dst + (((c2 * 2 + 1) ^ sw) * 8)) = o1;
        }
    }
}

// ============== MFMA GEMM + packed-key top-2 (round-5 proven, byte-identical) ==============

__global__ __launch_bounds__(256, 4)
void mfma_argmin2(const short* __restrict__ ET3, const short* __restrict__ ZT3,
                  const float* __restrict__ enormB, uint2* __restrict__ pv) {
    __shared__ char smem[32768];
    const int t    = threadIdx.x;
    const int wid  = t >> 6, lane = t & 63;
    const int quad = lane >> 4, l16 = lane & 15;
    const int wm   = wid >> 1, wn = wid & 1;
    const int stripe = blockIdx.x >> 7;
    const int n0     = (blockIdx.x & 127) * 128;
    const int swz    = (l16 & 7);

    unsigned r1[4], r2[4];
#pragma unroll
    for (int fj = 0; fj < 4; ++fj) { r1[fj] = 0xFFFFFFFFu; r2[fj] = 0xFFFFFFFFu; }

#pragma unroll 1
    for (int cc = 0; cc < 8; ++cc) {
        const int c0 = stripe * 1024 + cc * 128;
        f32x4 acc[4][4];
#pragma unroll
        for (int fi = 0; fi < 4; ++fi)
#pragma unroll
            for (int fj = 0; fj < 4; ++fj) acc[fi][fj] = (f32x4){0.f, 0.f, 0.f, 0.f};

#pragma unroll 1
        for (int dcb = 0; dcb < 4; ++dcb) {
            __syncthreads();
            const char* gA = (const char*)ET3 + ((size_t)dcb * K_    + c0) * 128;
            const char* gB = (const char*)ZT3 + ((size_t)dcb * N_TOT + n0) * 128;
#pragma unroll
            for (int j = 0; j < 4; ++j) {
                int off = j * 4096 + t * 16;
                GLOAD_LDS16(gA + off, smem + off);
                GLOAD_LDS16(gB + off, smem + 16384 + off);
            }
            __syncthreads();
#pragma unroll
            for (int dc2 = 0; dc2 < 2; ++dc2) {
                bf16x8 af[4], bfv[4];
                const int chm = ((dc2 * 4 + quad) ^ swz) * 16;
#pragma unroll
                for (int fi = 0; fi < 4; ++fi)
                    af[fi] = *(const bf16x8*)(smem + (wm*64 + fi*16 + l16)*128 + chm);
#pragma unroll
                for (int fj = 0; fj < 4; ++fj)
                    bfv[fj] = *(const bf16x8*)(smem + 16384 + (wn*64 + fj*16 + l16)*128 + chm);
#pragma unroll
                for (int fi = 0; fi < 4; ++fi)
#pragma unroll
                    for (int fj = 0; fj < 4; ++fj)
                        acc[fi][fj] = __builtin_amdgcn_mfma_f32_16x16x32_bf16(
                            af[fi], bfv[fj], acc[fi][fj], 0, 0, 0);
            }
        }

        float ekv[4][4];
#pragma unroll
        for (int fi = 0; fi < 4; ++fi) {
            float4 e4 = *(const float4*)(enormB + c0 + wm*64 + fi*16 + quad*4);
            ekv[fi][0]=e4.x; ekv[fi][1]=e4.y; ekv[fi][2]=e4.z; ekv[fi][3]=e4.w;
        }
#pragma unroll
        for (int fj = 0; fj < 4; ++fj) {
#pragma unroll
            for (int fi = 0; fi < 4; ++fi) {
                const unsigned cb = (unsigned)(c0 + wm*64 + fi*16 + quad*4);
                float s0 = fmaf(-2.f, acc[fi][fj].x, ekv[fi][0]);
                float s1 = fmaf(-2.f, acc[fi][fj].y, ekv[fi][1]);
                float s2 = fmaf(-2.f, acc[fi][fj].z, ekv[fi][2]);
                float s3 = fmaf(-2.f, acc[fi][fj].w, ekv[fi][3]);
                unsigned k0 = (__float_as_uint(s0) & 0xFFFFE000u) | (cb + 0u);
                unsigned k1 = (__float_as_uint(s1) & 0xFFFFE000u) | (cb + 1u);
                unsigned k2 = (__float_as_uint(s2) & 0xFFFFE000u) | (cb + 2u);
                unsigned k3 = (__float_as_uint(s3) & 0xFFFFE000u) | (cb + 3u);
                unsigned lo1 = min(k0, k1), hi1 = max(k0, k1);
                unsigned lo2 = min(k2, k3), hi2 = max(k2, k3);
                merge2(lo1, hi1, lo2, hi2);
                merge2(r1[fj], r2[fj], lo1, hi1);
            }
        }
    }

#pragma unroll
    for (int fj = 0; fj < 4; ++fj) {
        unsigned a1 = r1[fj], a2 = r2[fj];
#pragma unroll
        for (int m = 16; m <= 32; m <<= 1) {
            unsigned b1 = __shfl_xor(a1, m, 64);
            unsigned b2 = __shfl_xor(a2, m, 64);
            merge2(a1, a2, b1, b2);
        }
        if (quad == 0) {
            int n = n0 + wn*64 + fj*16 + l16;
            pv[(size_t)(stripe * 2 + wm) * N_TOT + n] = make_uint2(a1, a2);
        }
    }
}

// ============== phase A: znorm (ordered sum, identical) + window classify ==============

template <int NG>
__global__ __launch_bounds__(256)
void phaseA_z(const uint2* __restrict__ pv, const float* __restrict__ zpart,
              float* __restrict__ znorm, int* __restrict__ fidx,
              float* __restrict__ out_idx, int* __restrict__ wl,
              int* __restrict__ wl_cnt, float* __restrict__ out_loss) {
    int n = blockIdx.x * 256 + threadIdx.x;
    if (n == 0) *out_loss = 0.f;
    float zsum = 0.f;
#pragma unroll
    for (int dc = 0; dc < 16; ++dc) zsum += zpart[(size_t)dc * N_TOT + n];
    znorm[n] = zsum;
    uint2 pp[NG];
    unsigned mn = 0xFFFFFFFFu;
#pragma unroll
    for (int g = 0; g < NG; ++g) {
        pp[g] = pv[(size_t)g * N_TOT + n];
        mn = min(mn, pp[g].x);
    }
    float smin  = __uint_as_float(mn & 0xFFFFE000u);
    unsigned th = __float_as_uint(smin + DELTA_) | 8191u;
    int cnt = 0;
#pragma unroll
    for (int g = 0; g < NG; ++g) {
        cnt += (pp[g].x <= th) ? 1 : 0;
        cnt += (pp[g].y <= th) ? 1 : 0;
    }
    if (cnt > 1) {
        int slot = atomicAdd(wl_cnt, 1);
        wl[slot] = n;
    } else {
        int c = (int)(mn & 8191u);
        fidx[n] = c;
        out_idx[n] = (float)c;
    }
}

// ============== phase B: one wave per recheck row (exact chain, unchanged) ==============

template <int NG>
__global__ __launch_bounds__(256)
void recheck_t(const uint2* __restrict__ pv, const float* __restrict__ znorm,
               const float* __restrict__ enorm, const float* __restrict__ z,
               const float* __restrict__ emb, const int* __restrict__ wl,
               const int* __restrict__ wl_cnt, int* __restrict__ fidx,
               float* __restrict__ out_idx) {
    __shared__ float zrow[4][256];
    const int lane = threadIdx.x & 63;
    const int wslot = threadIdx.x >> 6;
    const int gwave = (blockIdx.x * 256 + threadIdx.x) >> 6;
    const int nwaves = (gridDim.x * 256) >> 6;
    int total = *wl_cnt;
    total = min(max(total, 0), N_TOT);       // clamp (profiling-replay robustness)

    for (int i = gwave; i < total; i += nwaves) {
        int n = wl[i];
        unsigned key = 0xFFFFFFFFu;
        if (lane < 2 * NG) {
            uint2 p = pv[(size_t)(lane >> 1) * N_TOT + n];
            key = (lane & 1) ? p.y : p.x;
        }
        unsigned mn = key;
#pragma unroll
        for (int m = 1; m < 64; m <<= 1) mn = min(mn, __shfl_xor(mn, m, 64));
        float smin  = __uint_as_float(mn & 0xFFFFE000u);
        unsigned th = __float_as_uint(smin + DELTA_) | 8191u;

        const int b = n >> 10, sp = n & 1023;
        const float* zr = z + (size_t)b * ZB + sp;
#pragma unroll
        for (int j = 0; j < 4; ++j)
            zrow[wslot][lane + j * 64] = zr[(size_t)(lane + j * 64) * SP];
        float zn = znorm[n];

        unsigned lexlo = 0xFFFFFFFFu, lexhi = 0xFFFFFFFFu;
        if (key <= th) {
            int c = (int)(key & 8191u);
            const float* er = emb + (size_t)c * D_;
            float dot = 0.f;
#pragma unroll 8
            for (int d = 0; d < D_; ++d)
                dot = fmaf(zrow[wslot][d], er[d], dot);
            float s = (zn + enorm[c]) - 2.f * dot;
            unsigned sb = __float_as_uint(s);
            lexhi = sb >> 19;
            lexlo = (sb << 13) | (unsigned)c;
        }
#pragma unroll
        for (int m = 1; m < 64; m <<= 1) {
            unsigned olo = __shfl_xor(lexlo, m, 64);
            unsigned ohi = __shfl_xor(lexhi, m, 64);
            if (ohi < lexhi || (ohi == lexhi && olo < lexlo)) { lexhi = ohi; lexlo = olo; }
        }
        if (lane == 0) {
            int c = (int)(lexlo & 8191u);
            fidx[n] = c;
            out_idx[n] = (float)c;
        }
    }
}

// ======================= output / loss (unchanged) =======================

__global__ __launch_bounds__(256)
void output_kernel2(const float* __restrict__ z, const float* __restrict__ emb,
                    const int* __restrict__ fidx, float* __restrict__ out,
                    float* __restrict__ loss) {
    __shared__ float eL[32][257];
    __shared__ int   fid[32];
    __shared__ float red[4];
    const int nb = blockIdx.x;
    const int n0 = nb * 32;
    const int b  = n0 >> 10;
    const int s0 = n0 & 1023;
    const int t  = threadIdx.x;
    if (t < 32) fid[t] = fidx[n0 + t];
    __syncthreads();
#pragma unroll
    for (int i = 0; i < 8; ++i) {
        int p = t + i * 256;
        int row = p >> 6, q = p & 63;
        float4 v = *(const float4*)(emb + (size_t)fid[row] * D_ + q * 4);
        eL[row][q*4+0] = v.x; eL[row][q*4+1] = v.y;
        eL[row][q*4+2] = v.z; eL[row][q*4+3] = v.w;
    }
    __syncthreads();
    const int sl = t & 31, dg = t >> 5;
    float lsum = 0.f;
#pragma unroll
    for (int i = 0; i < 32; ++i) {
        int d = dg * 32 + i;
        size_t off = ((size_t)(b * D_ + d)) * SP + s0 + sl;
        float zv = z[off];
        float q  = eL[sl][d];
        float diff = q - zv;
        out[off] = zv + diff;
        lsum += diff * diff;
    }
    for (int m = 1; m < 64; m <<= 1) lsum += __shfl_xor(lsum, m, 64);
    if ((t & 63) == 0) red[t >> 6] = lsum;
    __syncthreads();
    if (t == 0) {
        float tot = (red[0] + red[1] + red[2] + red[3])
                    * (1.25f / (float)(B_ * SP * D_));
        atomicAdd(loss, tot);
    }
}

// ======================= launch =======================
// ws layout (floats) — NEED = 15,991,296 B (proven in rounds 6-7):
//   enorm [0,8192) enormB [8192,16384) znorm [16384,32768) fidx [32768,49152)
//   wl_cnt 49152 (pad 49216) wl [49216,65600) (pad 65664)
//   zpart [65664,327808)   pv16 [327808,852096)
//   ET3 (short) [852096,1900672)   ZT3 (short) [1900672,3997824)

extern "C" void kernel_launch(void* const* d_in, const int* in_sizes, int n_in,
                              void* d_out, int out_size, void* d_ws, size_t ws_size,
                              hipStream_t stream) {
    const float* z   = (const float*)d_in[0];
    const float* emb = (const float*)d_in[1];
    float* out = (float*)d_out;
    float* w   = (float*)d_ws;

    float* enorm  = w;
    float* enormB = w + 8192;
    float* znorm  = w + 16384;
    int*   fidx   = (int*)(w + 32768);
    int*   wl_cnt = (int*)(w + 49152);
    int*   wl     = (int*)(w + 49216);
    float* zpart  = w + 65664;
    uint2* pv     = (uint2*)(w + 327808);
    short* ET3    = (short*)(w + 852096);
    short* ZT3    = (short*)(w + 1900672);

    float* out0     = out;
    float* out_loss = out + (size_t)B_ * D_ * SP;
    float* out_idx  = out_loss + 1;

    prep_kernel<<<2304, 256, 0, stream>>>(emb, z, ET3, ZT3, zpart,
                                          enorm, enormB, wl_cnt);
    mfma_argmin2<<<1024, 256, 0, stream>>>(ET3, ZT3, enormB, pv);
    phaseA_z<16><<<N_TOT / 256, 256, 0, stream>>>(pv, zpart, znorm, fidx,
                                                  out_idx, wl, wl_cnt, out_loss);
    recheck_t<16><<<256, 256, 0, stream>>>(pv, znorm, enorm, z, emb,
                                           wl, wl_cnt, fidx, out_idx);
    output_kernel2<<<N_TOT / 32, 256, 0, stream>>>(z, emb, fidx, out0, out_loss);
}

// Round 9
// 226.370 us; speedup vs baseline: 1.4218x; 1.0373x over previous
//
#include <hip/hip_runtime.h>

#define B_    16
#define D_    256
#define H_    32
#define W_    32
#define SP    1024        // H_*W_
#define N_TOT 16384       // B_*SP
#define K_    8192
#define ZB    (D_*SP)     // floats per batch in z

#define BIAS_  0.03125f
#define DELTA_ 2.5e-4f

typedef __attribute__((ext_vector_type(8))) short bf16x8;
typedef __attribute__((ext_vector_type(4))) short bf16x4;
typedef __attribute__((ext_vector_type(4))) float f32x4;

#define GLOAD_LDS16(g, l) \
    __builtin_amdgcn_global_load_lds((const __attribute__((address_space(1))) void*)(g), \
                                     (__attribute__((address_space(3))) void*)(l), 16, 0, 0)

__device__ __forceinline__ unsigned short f2bf(float f) {
    unsigned u = __float_as_uint(f);
    u += 0x7FFFu + ((u >> 16) & 1u);          // RNE
    return (unsigned short)(u >> 16);
}

// merge two sorted pairs (a1<=a2), (b1<=b2) -> top-2 in (a1,a2). u32 lex keys.
__device__ __forceinline__ void merge2(unsigned &a1, unsigned &a2,
                                       unsigned b1, unsigned b2) {
    unsigned m1  = min(a1, b1);
    unsigned hi  = max(a1, b1);
    unsigned sel = (a1 < b1) ? a2 : b2;
    a2 = min(hi, sel);
    a1 = m1;
}

// ================= fused prep: e-convert+enorm  |  z-convert+zpart =================
// blocks [0,2048): per-code enorm (tree IDENTICAL to r1-8) + tiled-swizzled ET3
// blocks [2048,2304): zpart chunks (IDENTICAL 16x16 trees) + tiled-swizzled ZT3
// Also zeroes out_loss (runs strictly before tail_fused on the stream).

__global__ __launch_bounds__(256)
void prep_kernel(const float* __restrict__ emb, const float* __restrict__ z,
                 short* __restrict__ ET3, short* __restrict__ ZT3,
                 float* __restrict__ zpart, float* __restrict__ enorm,
                 float* __restrict__ enormB, float* __restrict__ out_loss) {
    const int bx = blockIdx.x;
    const int t  = threadIdx.x;
    if (bx < 2048) {
        int k = bx * 4 + (t >> 6);
        int l = t & 63;
        float4 v = *(const float4*)(emb + (size_t)k * D_ + l * 4);
        float sum = v.x*v.x + v.y*v.y + v.z*v.z + v.w*v.w;
        for (int m = 1; m < 64; m <<= 1) sum += __shfl_xor(sum, m, 64);
        if (l == 0) { enorm[k] = sum; enormB[k] = sum + BIAS_; }
        int dcb  = l >> 4;
        int c    = (l >> 1) & 7;
        int half = l & 1;
        bf16x4 o;
        o[0] = (short)f2bf(v.x); o[1] = (short)f2bf(v.y);
        o[2] = (short)f2bf(v.z); o[3] = (short)f2bf(v.w);
        *(bf16x4*)(ET3 + ((size_t)dcb * K_ + k) * 64 + ((c ^ (k & 7)) * 8) + half * 4) = o;
    } else {
        int bz  = bx - 2048;
        if (bz == 0 && t == 0) *out_loss = 0.f;
        int dcb = bz >> 6;
        int st  = bz & 63;
        int n   = st * 256 + t;
        int b   = n >> 10;
        int s   = n & 1023;
        const float* zb = z + (size_t)b * ZB + (size_t)(dcb * 64) * SP + s;
        short* dst = ZT3 + ((size_t)dcb * N_TOT + n) * 64;
        int sw = n & 7;
#pragma unroll
        for (int c2 = 0; c2 < 4; ++c2) {
            float vv[16];
#pragma unroll
            for (int dd = 0; dd < 16; ++dd)
                vv[dd] = zb[(size_t)(c2 * 16 + dd) * SP];
            float sum = 0.f;
#pragma unroll
            for (int dd = 0; dd < 16; ++dd) {
                float v = vv[dd];
                sum += v * v;
            }
            zpart[(size_t)(dcb * 4 + c2) * N_TOT + n] = sum;
            bf16x8 o0, o1;
#pragma unroll
            for (int j = 0; j < 8; ++j) { o0[j] = (short)f2bf(vv[j]);
                                          o1[j] = (short)f2bf(vv[8 + j]); }
            *(bf16x8*)(dst + (((c2 * 2)     ^ sw) * 8)) = o0;
            *(bf16x8*)(dst + (((c2 * 2 + 1) ^ sw) * 8)) = o1;
        }
    }
}

// ============== MFMA GEMM + packed-key top-2 (round-5/8 proven, byte-identical) ==============

__global__ __launch_bounds__(256, 4)
void mfma_argmin2(const short* __restrict__ ET3, const short* __restrict__ ZT3,
                  const float* __restrict__ enormB, uint2* __restrict__ pv) {
    __shared__ char smem[32768];
    const int t    = threadIdx.x;
    const int wid  = t >> 6, lane = t & 63;
    const int quad = lane >> 4, l16 = lane & 15;
    const int wm   = wid >> 1, wn = wid & 1;
    const int stripe = blockIdx.x >> 7;
    const int n0     = (blockIdx.x & 127) * 128;
    const int swz    = (l16 & 7);

    unsigned r1[4], r2[4];
#pragma unroll
    for (int fj = 0; fj < 4; ++fj) { r1[fj] = 0xFFFFFFFFu; r2[fj] = 0xFFFFFFFFu; }

#pragma unroll 1
    for (int cc = 0; cc < 8; ++cc) {
        const int c0 = stripe * 1024 + cc * 128;
        f32x4 acc[4][4];
#pragma unroll
        for (int fi = 0; fi < 4; ++fi)
#pragma unroll
            for (int fj = 0; fj < 4; ++fj) acc[fi][fj] = (f32x4){0.f, 0.f, 0.f, 0.f};

#pragma unroll 1
        for (int dcb = 0; dcb < 4; ++dcb) {
            __syncthreads();
            const char* gA = (const char*)ET3 + ((size_t)dcb * K_    + c0) * 128;
            const char* gB = (const char*)ZT3 + ((size_t)dcb * N_TOT + n0) * 128;
#pragma unroll
            for (int j = 0; j < 4; ++j) {
                int off = j * 4096 + t * 16;
                GLOAD_LDS16(gA + off, smem + off);
                GLOAD_LDS16(gB + off, smem + 16384 + off);
            }
            __syncthreads();
#pragma unroll
            for (int dc2 = 0; dc2 < 2; ++dc2) {
                bf16x8 af[4], bfv[4];
                const int chm = ((dc2 * 4 + quad) ^ swz) * 16;
#pragma unroll
                for (int fi = 0; fi < 4; ++fi)
                    af[fi] = *(const bf16x8*)(smem + (wm*64 + fi*16 + l16)*128 + chm);
#pragma unroll
                for (int fj = 0; fj < 4; ++fj)
                    bfv[fj] = *(const bf16x8*)(smem + 16384 + (wn*64 + fj*16 + l16)*128 + chm);
#pragma unroll
                for (int fi = 0; fi < 4; ++fi)
#pragma unroll
                    for (int fj = 0; fj < 4; ++fj)
                        acc[fi][fj] = __builtin_amdgcn_mfma_f32_16x16x32_bf16(
                            af[fi], bfv[fj], acc[fi][fj], 0, 0, 0);
            }
        }

        float ekv[4][4];
#pragma unroll
        for (int fi = 0; fi < 4; ++fi) {
            float4 e4 = *(const float4*)(enormB + c0 + wm*64 + fi*16 + quad*4);
            ekv[fi][0]=e4.x; ekv[fi][1]=e4.y; ekv[fi][2]=e4.z; ekv[fi][3]=e4.w;
        }
#pragma unroll
        for (int fj = 0; fj < 4; ++fj) {
#pragma unroll
            for (int fi = 0; fi < 4; ++fi) {
                const unsigned cb = (unsigned)(c0 + wm*64 + fi*16 + quad*4);
                float s0 = fmaf(-2.f, acc[fi][fj].x, ekv[fi][0]);
                float s1 = fmaf(-2.f, acc[fi][fj].y, ekv[fi][1]);
                float s2 = fmaf(-2.f, acc[fi][fj].z, ekv[fi][2]);
                float s3 = fmaf(-2.f, acc[fi][fj].w, ekv[fi][3]);
                unsigned k0 = (__float_as_uint(s0) & 0xFFFFE000u) | (cb + 0u);
                unsigned k1 = (__float_as_uint(s1) & 0xFFFFE000u) | (cb + 1u);
                unsigned k2 = (__float_as_uint(s2) & 0xFFFFE000u) | (cb + 2u);
                unsigned k3 = (__float_as_uint(s3) & 0xFFFFE000u) | (cb + 3u);
                unsigned lo1 = min(k0, k1), hi1 = max(k0, k1);
                unsigned lo2 = min(k2, k3), hi2 = max(k2, k3);
                merge2(lo1, hi1, lo2, hi2);
                merge2(r1[fj], r2[fj], lo1, hi1);
            }
        }
    }

#pragma unroll
    for (int fj = 0; fj < 4; ++fj) {
        unsigned a1 = r1[fj], a2 = r2[fj];
#pragma unroll
        for (int m = 16; m <= 32; m <<= 1) {
            unsigned b1 = __shfl_xor(a1, m, 64);
            unsigned b2 = __shfl_xor(a2, m, 64);
            merge2(a1, a2, b1, b2);
        }
        if (quad == 0) {
            int n = n0 + wn*64 + fj*16 + l16;
            pv[(size_t)(stripe * 2 + wm) * N_TOT + n] = make_uint2(a1, a2);
        }
    }
}

// ============== fused tail: classify + block-local recheck + output + loss ==============
// Grid 256 blocks x 64 rows. All numerics-bearing expressions identical to the
// proven rounds: window classify (phaseA), zn 16-term sequential tree (znorm),
// exact fp32 dot chain (recheck), fl(z + fl(q - z)) output.

__global__ __launch_bounds__(256)
void tail_fused(const uint2* __restrict__ pv, const float* __restrict__ zpart,
                const float* __restrict__ enorm, const float* __restrict__ z,
                const float* __restrict__ emb, float* __restrict__ out,
                float* __restrict__ out_idx, float* __restrict__ loss) {
    __shared__ float eL[64][257];     // 64.3 KB: emb rows for the 64 n's
    __shared__ float zrow[4][256];    // per-wave recheck z-row slots
    __shared__ int   fid[64];
    __shared__ int   wlL[64];
    __shared__ int   nflag;
    __shared__ float red[4];

    const int t  = threadIdx.x;
    const int n0 = blockIdx.x * 64;
    const int b  = n0 >> 10;
    const int s0 = n0 & 1023;

    if (t == 0) nflag = 0;
    __syncthreads();

    // ---- phase 1: classify 64 rows (identical window expressions) ----
    if (t < 64) {
        int n = n0 + t;
        uint2 pp[16];
        unsigned mn = 0xFFFFFFFFu;
#pragma unroll
        for (int g = 0; g < 16; ++g) {
            pp[g] = pv[(size_t)g * N_TOT + n];
            mn = min(mn, pp[g].x);
        }
        float smin  = __uint_as_float(mn & 0xFFFFE000u);
        unsigned th = __float_as_uint(smin + DELTA_) | 8191u;
        int cnt = 0;
#pragma unroll
        for (int g = 0; g < 16; ++g) {
            cnt += (pp[g].x <= th) ? 1 : 0;
            cnt += (pp[g].y <= th) ? 1 : 0;
        }
        if (cnt > 1) {
            int slot = atomicAdd(&nflag, 1);
            wlL[slot] = t;
        } else {
            int c = (int)(mn & 8191u);
            fid[t] = c;
            out_idx[n] = (float)c;
        }
    }
    __syncthreads();

    // ---- phase 2: block-local recheck, one wave per flagged row ----
    const int lane = t & 63;
    const int wid  = t >> 6;
    const int nf   = nflag;
    for (int i = wid; i < nf; i += 4) {
        int r = wlL[i];
        int n = n0 + r;
        unsigned key = 0xFFFFFFFFu;
        if (lane < 32) {
            uint2 p = pv[(size_t)(lane >> 1) * N_TOT + n];
            key = (lane & 1) ? p.y : p.x;
        }
        unsigned mn = key;
#pragma unroll
        for (int m = 1; m < 64; m <<= 1) mn = min(mn, __shfl_xor(mn, m, 64));
        float smin  = __uint_as_float(mn & 0xFFFFE000u);
        unsigned th = __float_as_uint(smin + DELTA_) | 8191u;

        // zn: bit-identical sequential 16-term sum over zpart (znorm's tree)
        float zp = 0.f;
        if (lane < 16) zp = zpart[(size_t)lane * N_TOT + n];
        float zn = 0.f;
#pragma unroll
        for (int dc = 0; dc < 16; ++dc) zn += __shfl(zp, dc, 64);

        const float* zr = z + (size_t)b * ZB + (s0 + r);
#pragma unroll
        for (int j = 0; j < 4; ++j)
            zrow[wid][lane + j * 64] = zr[(size_t)(lane + j * 64) * SP];

        unsigned lexlo = 0xFFFFFFFFu, lexhi = 0xFFFFFFFFu;
        if (key <= th) {
            int c = (int)(key & 8191u);
            const float* er = emb + (size_t)c * D_;
            float dot = 0.f;
#pragma unroll 8
            for (int d = 0; d < D_; ++d)
                dot = fmaf(zrow[wid][d], er[d], dot);
            float s = (zn + enorm[c]) - 2.f * dot;
            unsigned sb = __float_as_uint(s);
            lexhi = sb >> 19;
            lexlo = (sb << 13) | (unsigned)c;
        }
#pragma unroll
        for (int m = 1; m < 64; m <<= 1) {
            unsigned olo = __shfl_xor(lexlo, m, 64);
            unsigned ohi = __shfl_xor(lexhi, m, 64);
            if (ohi < lexhi || (ohi == lexhi && olo < lexlo)) { lexhi = ohi; lexlo = olo; }
        }
        if (lane == 0) {
            int c = (int)(lexlo & 8191u);
            fid[r] = c;
            out_idx[n] = (float)c;
        }
    }
    __syncthreads();

    // ---- phase 3: stage the 64 selected emb rows into LDS ----
#pragma unroll
    for (int i = 0; i < 16; ++i) {
        int p = t + i * 256;             // 4096 float4 slots: row = p>>6, q = p&63
        int row = p >> 6, q = p & 63;
        float4 v = *(const float4*)(emb + (size_t)fid[row] * D_ + q * 4);
        eL[row][q*4+0] = v.x; eL[row][q*4+1] = v.y;
        eL[row][q*4+2] = v.z; eL[row][q*4+3] = v.w;
    }
    __syncthreads();

    // ---- phase 4: stream out + loss (float4 over spatial) ----
    const int sq = t & 15, dg = t >> 4;
    float lsum = 0.f;
#pragma unroll
    for (int i = 0; i < 16; ++i) {
        int d = dg * 16 + i;
        size_t off = ((size_t)(b * D_ + d)) * SP + s0 + sq * 4;
        float4 z4 = *(const float4*)(z + off);
        float q0 = eL[sq*4+0][d], q1 = eL[sq*4+1][d];
        float q2 = eL[sq*4+2][d], q3 = eL[sq*4+3][d];
        float d0 = q0 - z4.x, d1 = q1 - z4.y;     // fl(q - z)
        float d2 = q2 - z4.z, d3 = q3 - z4.w;
        float4 o4 = make_float4(z4.x + d0, z4.y + d1,   // fl(z + fl(q-z))
                                z4.z + d2, z4.w + d3);
        *(float4*)(out + off) = o4;
        lsum += d0*d0; lsum += d1*d1; lsum += d2*d2; lsum += d3*d3;
    }
    for (int m = 1; m < 64; m <<= 1) lsum += __shfl_xor(lsum, m, 64);
    if ((t & 63) == 0) red[t >> 6] = lsum;
    __syncthreads();
    if (t == 0) {
        float tot = (red[0] + red[1] + red[2] + red[3])
                    * (1.25f / (float)(B_ * SP * D_));
        atomicAdd(loss, tot);
    }
}

// ======================= launch =======================
// ws layout (floats) — NEED = 15,794,176 B (< proven grant):
//   enorm [0,8192)  enormB [8192,16384)  zpart [16384,278528)
//   pv16 [278528,802816)
//   ET3 (short) [802816,1851392)   ZT3 (short) [1851392,3948544)

extern "C" void kernel_launch(void* const* d_in, const int* in_sizes, int n_in,
                              void* d_out, int out_size, void* d_ws, size_t ws_size,
                              hipStream_t stream) {
    const float* z   = (const float*)d_in[0];
    const float* emb = (const float*)d_in[1];
    float* out = (float*)d_out;
    float* w   = (float*)d_ws;

    float* enorm  = w;
    float* enormB = w + 8192;
    float* zpart  = w + 16384;
    uint2* pv     = (uint2*)(w + 278528);
    short* ET3    = (short*)(w + 802816);
    short* ZT3    = (short*)(w + 1851392);

    float* out0     = out;
    float* out_loss = out + (size_t)B_ * D_ * SP;
    float* out_idx  = out_loss + 1;

    prep_kernel<<<2304, 256, 0, stream>>>(emb, z, ET3, ZT3, zpart,
                                          enorm, enormB, out_loss);
    mfma_argmin2<<<1024, 256, 0, stream>>>(ET3, ZT3, enormB, pv);
    tail_fused<<<256, 256, 0, stream>>>(pv, zpart, enorm, z, emb,
                                        out0, out_idx, out_loss);
}

// Round 10
// 204.930 us; speedup vs baseline: 1.5706x; 1.1046x over previous
//
#include <hip/hip_runtime.h>

#define B_    16
#define D_    256
#define H_    32
#define W_    32
#define SP    1024        // H_*W_
#define N_TOT 16384       // B_*SP
#define K_    8192
#define ZB    (D_*SP)     // floats per batch in z

#define BIAS_  0.03125f
#define DELTA_ 2.5e-4f

typedef __attribute__((ext_vector_type(8))) short bf16x8;
typedef __attribute__((ext_vector_type(4))) short bf16x4;
typedef __attribute__((ext_vector_type(4))) float f32x4;

#define GLOAD_LDS16(g, l) \
    __builtin_amdgcn_global_load_lds((const __attribute__((address_space(1))) void*)(g), \
                                     (__attribute__((address_space(3))) void*)(l), 16, 0, 0)

__device__ __forceinline__ unsigned short f2bf(float f) {
    unsigned u = __float_as_uint(f);
    u += 0x7FFFu + ((u >> 16) & 1u);          // RNE
    return (unsigned short)(u >> 16);
}

// merge two sorted pairs (a1<=a2), (b1<=b2) -> top-2 in (a1,a2). u32 lex keys.
__device__ __forceinline__ void merge2(unsigned &a1, unsigned &a2,
                                       unsigned b1, unsigned b2) {
    unsigned m1  = min(a1, b1);
    unsigned hi  = max(a1, b1);
    unsigned sel = (a1 < b1) ? a2 : b2;
    a2 = min(hi, sel);
    a1 = m1;
}

// ================= fused prep: e-convert+enorm  |  z-convert+zpart =================
// blocks [0,2048): per-code enorm (tree IDENTICAL to r1-9) + tiled-swizzled ET3
// blocks [2048,3072): z-section, now 4 threads per row (one per c2 chunk):
//   per-chunk 16-term sequential sums and all addresses BYTE-IDENTICAL to r5-9,
//   just distributed across threads for 4x block parallelism.

__global__ __launch_bounds__(256)
void prep_kernel(const float* __restrict__ emb, const float* __restrict__ z,
                 short* __restrict__ ET3, short* __restrict__ ZT3,
                 float* __restrict__ zpart, float* __restrict__ enorm,
                 float* __restrict__ enormB, float* __restrict__ out_loss) {
    const int bx = blockIdx.x;
    const int t  = threadIdx.x;
    if (bx < 2048) {
        int k = bx * 4 + (t >> 6);
        int l = t & 63;
        float4 v = *(const float4*)(emb + (size_t)k * D_ + l * 4);
        float sum = v.x*v.x + v.y*v.y + v.z*v.z + v.w*v.w;
        for (int m = 1; m < 64; m <<= 1) sum += __shfl_xor(sum, m, 64);
        if (l == 0) { enorm[k] = sum; enormB[k] = sum + BIAS_; }
        int dcb  = l >> 4;
        int c    = (l >> 1) & 7;
        int half = l & 1;
        bf16x4 o;
        o[0] = (short)f2bf(v.x); o[1] = (short)f2bf(v.y);
        o[2] = (short)f2bf(v.z); o[3] = (short)f2bf(v.w);
        *(bf16x4*)(ET3 + ((size_t)dcb * K_ + k) * 64 + ((c ^ (k & 7)) * 8) + half * 4) = o;
    } else {
        int bz  = bx - 2048;                 // 0..1023
        if (bz == 0 && t == 0) *out_loss = 0.f;
        int dcb  = bz & 3;
        int tile = bz >> 2;                  // 0..255 (64 rows each)
        int nl   = t >> 2;                   // row within tile
        int c2   = t & 2 ? (t & 3) : (t & 3);// c2 = t & 3
        c2 = t & 3;
        int n = tile * 64 + nl;
        int b = n >> 10;
        int s = n & 1023;
        const float* zb = z + (size_t)b * ZB + (size_t)(dcb * 64) * SP + s;
        short* dst = ZT3 + ((size_t)dcb * N_TOT + n) * 64;
        int sw = n & 7;
        float vv[16];
#pragma unroll
        for (int dd = 0; dd < 16; ++dd)
            vv[dd] = zb[(size_t)(c2 * 16 + dd) * SP];
        float sum = 0.f;
#pragma unroll
        for (int dd = 0; dd < 16; ++dd) {
            float v = vv[dd];
            sum += v * v;
        }
        zpart[(size_t)(dcb * 4 + c2) * N_TOT + n] = sum;
        bf16x8 o0, o1;
#pragma unroll
        for (int j = 0; j < 8; ++j) { o0[j] = (short)f2bf(vv[j]);
                                      o1[j] = (short)f2bf(vv[8 + j]); }
        *(bf16x8*)(dst + (((c2 * 2)     ^ sw) * 8)) = o0;
        *(bf16x8*)(dst + (((c2 * 2 + 1) ^ sw) * 8)) = o1;
    }
}

// ============== MFMA GEMM + packed-key top-2 (round-5/8/9 proven, byte-identical) ==============

__global__ __launch_bounds__(256, 4)
void mfma_argmin2(const short* __restrict__ ET3, const short* __restrict__ ZT3,
                  const float* __restrict__ enormB, uint2* __restrict__ pv) {
    __shared__ char smem[32768];
    const int t    = threadIdx.x;
    const int wid  = t >> 6, lane = t & 63;
    const int quad = lane >> 4, l16 = lane & 15;
    const int wm   = wid >> 1, wn = wid & 1;
    const int stripe = blockIdx.x >> 7;
    const int n0     = (blockIdx.x & 127) * 128;
    const int swz    = (l16 & 7);

    unsigned r1[4], r2[4];
#pragma unroll
    for (int fj = 0; fj < 4; ++fj) { r1[fj] = 0xFFFFFFFFu; r2[fj] = 0xFFFFFFFFu; }

#pragma unroll 1
    for (int cc = 0; cc < 8; ++cc) {
        const int c0 = stripe * 1024 + cc * 128;
        f32x4 acc[4][4];
#pragma unroll
        for (int fi = 0; fi < 4; ++fi)
#pragma unroll
            for (int fj = 0; fj < 4; ++fj) acc[fi][fj] = (f32x4){0.f, 0.f, 0.f, 0.f};

#pragma unroll 1
        for (int dcb = 0; dcb < 4; ++dcb) {
            __syncthreads();
            const char* gA = (const char*)ET3 + ((size_t)dcb * K_    + c0) * 128;
            const char* gB = (const char*)ZT3 + ((size_t)dcb * N_TOT + n0) * 128;
#pragma unroll
            for (int j = 0; j < 4; ++j) {
                int off = j * 4096 + t * 16;
                GLOAD_LDS16(gA + off, smem + off);
                GLOAD_LDS16(gB + off, smem + 16384 + off);
            }
            __syncthreads();
#pragma unroll
            for (int dc2 = 0; dc2 < 2; ++dc2) {
                bf16x8 af[4], bfv[4];
                const int chm = ((dc2 * 4 + quad) ^ swz) * 16;
#pragma unroll
                for (int fi = 0; fi < 4; ++fi)
                    af[fi] = *(const bf16x8*)(smem + (wm*64 + fi*16 + l16)*128 + chm);
#pragma unroll
                for (int fj = 0; fj < 4; ++fj)
                    bfv[fj] = *(const bf16x8*)(smem + 16384 + (wn*64 + fj*16 + l16)*128 + chm);
#pragma unroll
                for (int fi = 0; fi < 4; ++fi)
#pragma unroll
                    for (int fj = 0; fj < 4; ++fj)
                        acc[fi][fj] = __builtin_amdgcn_mfma_f32_16x16x32_bf16(
                            af[fi], bfv[fj], acc[fi][fj], 0, 0, 0);
            }
        }

        float ekv[4][4];
#pragma unroll
        for (int fi = 0; fi < 4; ++fi) {
            float4 e4 = *(const float4*)(enormB + c0 + wm*64 + fi*16 + quad*4);
            ekv[fi][0]=e4.x; ekv[fi][1]=e4.y; ekv[fi][2]=e4.z; ekv[fi][3]=e4.w;
        }
#pragma unroll
        for (int fj = 0; fj < 4; ++fj) {
#pragma unroll
            for (int fi = 0; fi < 4; ++fi) {
                const unsigned cb = (unsigned)(c0 + wm*64 + fi*16 + quad*4);
                float s0 = fmaf(-2.f, acc[fi][fj].x, ekv[fi][0]);
                float s1 = fmaf(-2.f, acc[fi][fj].y, ekv[fi][1]);
                float s2 = fmaf(-2.f, acc[fi][fj].z, ekv[fi][2]);
                float s3 = fmaf(-2.f, acc[fi][fj].w, ekv[fi][3]);
                unsigned k0 = (__float_as_uint(s0) & 0xFFFFE000u) | (cb + 0u);
                unsigned k1 = (__float_as_uint(s1) & 0xFFFFE000u) | (cb + 1u);
                unsigned k2 = (__float_as_uint(s2) & 0xFFFFE000u) | (cb + 2u);
                unsigned k3 = (__float_as_uint(s3) & 0xFFFFE000u) | (cb + 3u);
                unsigned lo1 = min(k0, k1), hi1 = max(k0, k1);
                unsigned lo2 = min(k2, k3), hi2 = max(k2, k3);
                merge2(lo1, hi1, lo2, hi2);
                merge2(r1[fj], r2[fj], lo1, hi1);
            }
        }
    }

#pragma unroll
    for (int fj = 0; fj < 4; ++fj) {
        unsigned a1 = r1[fj], a2 = r2[fj];
#pragma unroll
        for (int m = 16; m <= 32; m <<= 1) {
            unsigned b1 = __shfl_xor(a1, m, 64);
            unsigned b2 = __shfl_xor(a2, m, 64);
            merge2(a1, a2, b1, b2);
        }
        if (quad == 0) {
            int n = n0 + wn*64 + fj*16 + l16;
            pv[(size_t)(stripe * 2 + wm) * N_TOT + n] = make_uint2(a1, a2);
        }
    }
}

// ============== fused tail: classify + block-local recheck + output + loss ==============
// 512 blocks x 32 rows (was 256 x 64): eL 33 KB -> 2 blocks/CU, 8 waves/CU.
// All numerics-bearing expressions identical to the proven rounds.

__global__ __launch_bounds__(256)
void tail_fused(const uint2* __restrict__ pv, const float* __restrict__ zpart,
                const float* __restrict__ enorm, const float* __restrict__ z,
                const float* __restrict__ emb, float* __restrict__ out,
                float* __restrict__ out_idx, float* __restrict__ loss) {
    __shared__ float eL[32][257];     // 32.9 KB: emb rows for the 32 n's
    __shared__ float zrow[4][256];    // per-wave recheck z-row slots
    __shared__ int   fid[32];
    __shared__ int   wlL[32];
    __shared__ int   nflag;
    __shared__ float red[4];

    const int t  = threadIdx.x;
    const int n0 = blockIdx.x * 32;
    const int b  = n0 >> 10;
    const int s0 = n0 & 1023;

    if (t == 0) nflag = 0;
    __syncthreads();

    // ---- phase 1: classify 32 rows (identical window expressions) ----
    if (t < 32) {
        int n = n0 + t;
        uint2 pp[16];
        unsigned mn = 0xFFFFFFFFu;
#pragma unroll
        for (int g = 0; g < 16; ++g) {
            pp[g] = pv[(size_t)g * N_TOT + n];
            mn = min(mn, pp[g].x);
        }
        float smin  = __uint_as_float(mn & 0xFFFFE000u);
        unsigned th = __float_as_uint(smin + DELTA_) | 8191u;
        int cnt = 0;
#pragma unroll
        for (int g = 0; g < 16; ++g) {
            cnt += (pp[g].x <= th) ? 1 : 0;
            cnt += (pp[g].y <= th) ? 1 : 0;
        }
        if (cnt > 1) {
            int slot = atomicAdd(&nflag, 1);
            wlL[slot] = t;
        } else {
            int c = (int)(mn & 8191u);
            fid[t] = c;
            out_idx[n] = (float)c;
        }
    }
    __syncthreads();

    // ---- phase 2: block-local recheck, one wave per flagged row ----
    const int lane = t & 63;
    const int wid  = t >> 6;
    const int nf   = nflag;
    for (int i = wid; i < nf; i += 4) {
        int r = wlL[i];
        int n = n0 + r;
        unsigned key = 0xFFFFFFFFu;
        if (lane < 32) {
            uint2 p = pv[(size_t)(lane >> 1) * N_TOT + n];
            key = (lane & 1) ? p.y : p.x;
        }
        unsigned mn = key;
#pragma unroll
        for (int m = 1; m < 64; m <<= 1) mn = min(mn, __shfl_xor(mn, m, 64));
        float smin  = __uint_as_float(mn & 0xFFFFE000u);
        unsigned th = __float_as_uint(smin + DELTA_) | 8191u;

        // zn: bit-identical sequential 16-term sum over zpart (znorm's tree)
        float zp = 0.f;
        if (lane < 16) zp = zpart[(size_t)lane * N_TOT + n];
        float zn = 0.f;
#pragma unroll
        for (int dc = 0; dc < 16; ++dc) zn += __shfl(zp, dc, 64);

        const float* zr = z + (size_t)b * ZB + (s0 + r);
#pragma unroll
        for (int j = 0; j < 4; ++j)
            zrow[wid][lane + j * 64] = zr[(size_t)(lane + j * 64) * SP];

        unsigned lexlo = 0xFFFFFFFFu, lexhi = 0xFFFFFFFFu;
        if (key <= th) {
            int c = (int)(key & 8191u);
            const float* er = emb + (size_t)c * D_;
            float dot = 0.f;
#pragma unroll 8
            for (int d = 0; d < D_; ++d)
                dot = fmaf(zrow[wid][d], er[d], dot);
            float s = (zn + enorm[c]) - 2.f * dot;
            unsigned sb = __float_as_uint(s);
            lexhi = sb >> 19;
            lexlo = (sb << 13) | (unsigned)c;
        }
#pragma unroll
        for (int m = 1; m < 64; m <<= 1) {
            unsigned olo = __shfl_xor(lexlo, m, 64);
            unsigned ohi = __shfl_xor(lexhi, m, 64);
            if (ohi < lexhi || (ohi == lexhi && olo < lexlo)) { lexhi = ohi; lexlo = olo; }
        }
        if (lane == 0) {
            int c = (int)(lexlo & 8191u);
            fid[r] = c;
            out_idx[n] = (float)c;
        }
    }
    __syncthreads();

    // ---- phase 3: stage the 32 selected emb rows into LDS ----
#pragma unroll
    for (int i = 0; i < 8; ++i) {
        int p = t + i * 256;             // 2048 float4 slots: row = p>>6, q = p&63
        int row = p >> 6, q = p & 63;
        float4 v = *(const float4*)(emb + (size_t)fid[row] * D_ + q * 4);
        eL[row][q*4+0] = v.x; eL[row][q*4+1] = v.y;
        eL[row][q*4+2] = v.z; eL[row][q*4+3] = v.w;
    }
    __syncthreads();

    // ---- phase 4: stream out + loss (float4 over spatial) ----
    const int sq = t & 7, dg = t >> 3;   // 8 float4-spans x 32 d-groups
    float lsum = 0.f;
#pragma unroll
    for (int i = 0; i < 8; ++i) {
        int d = dg * 8 + i;
        size_t off = ((size_t)(b * D_ + d)) * SP + s0 + sq * 4;
        float4 z4 = *(const float4*)(z + off);
        float q0 = eL[sq*4+0][d], q1 = eL[sq*4+1][d];
        float q2 = eL[sq*4+2][d], q3 = eL[sq*4+3][d];
        float d0 = q0 - z4.x, d1 = q1 - z4.y;     // fl(q - z)
        float d2 = q2 - z4.z, d3 = q3 - z4.w;
        float4 o4 = make_float4(z4.x + d0, z4.y + d1,   // fl(z + fl(q-z))
                                z4.z + d2, z4.w + d3);
        *(float4*)(out + off) = o4;
        lsum += d0*d0; lsum += d1*d1; lsum += d2*d2; lsum += d3*d3;
    }
    for (int m = 1; m < 64; m <<= 1) lsum += __shfl_xor(lsum, m, 64);
    if ((t & 63) == 0) red[t >> 6] = lsum;
    __syncthreads();
    if (t == 0) {
        float tot = (red[0] + red[1] + red[2] + red[3])
                    * (1.25f / (float)(B_ * SP * D_));
        atomicAdd(loss, tot);
    }
}

// ======================= launch =======================
// ws layout (floats) — NEED = 15,794,176 B (< proven grant):
//   enorm [0,8192)  enormB [8192,16384)  zpart [16384,278528)
//   pv16 [278528,802816)
//   ET3 (short) [802816,1851392)   ZT3 (short) [1851392,3948544)

extern "C" void kernel_launch(void* const* d_in, const int* in_sizes, int n_in,
                              void* d_out, int out_size, void* d_ws, size_t ws_size,
                              hipStream_t stream) {
    const float* z   = (const float*)d_in[0];
    const float* emb = (const float*)d_in[1];
    float* out = (float*)d_out;
    float* w   = (float*)d_ws;

    float* enorm  = w;
    float* enormB = w + 8192;
    float* zpart  = w + 16384;
    uint2* pv     = (uint2*)(w + 278528);
    short* ET3    = (short*)(w + 802816);
    short* ZT3    = (short*)(w + 1851392);

    float* out0     = out;
    float* out_loss = out + (size_t)B_ * D_ * SP;
    float* out_idx  = out_loss + 1;

    prep_kernel<<<3072, 256, 0, stream>>>(emb, z, ET3, ZT3, zpart,
                                          enorm, enormB, out_loss);
    mfma_argmin2<<<1024, 256, 0, stream>>>(ET3, ZT3, enormB, pv);
    tail_fused<<<512, 256, 0, stream>>>(pv, zpart, enorm, z, emb,
                                        out0, out_idx, out_loss);
}

// Round 11
// 204.497 us; speedup vs baseline: 1.5739x; 1.0021x over previous
//
#include <hip/hip_runtime.h>

#define B_    16
#define D_    256
#define H_    32
#define W_    32
#define SP    1024        // H_*W_
#define N_TOT 16384       // B_*SP
#define K_    8192
#define ZB    (D_*SP)     // floats per batch in z

#define BIAS_  0.03125f
#define DELTA_ 2.5e-4f

typedef __attribute__((ext_vector_type(8))) short bf16x8;
typedef __attribute__((ext_vector_type(4))) short bf16x4;
typedef __attribute__((ext_vector_type(4))) float f32x4;

#define GLOAD_LDS16(g, l) \
    __builtin_amdgcn_global_load_lds((const __attribute__((address_space(1))) void*)(g), \
                                     (__attribute__((address_space(3))) void*)(l), 16, 0, 0)

__device__ __forceinline__ unsigned short f2bf(float f) {
    unsigned u = __float_as_uint(f);
    u += 0x7FFFu + ((u >> 16) & 1u);          // RNE
    return (unsigned short)(u >> 16);
}

// merge two sorted pairs (a1<=a2), (b1<=b2) -> top-2 in (a1,a2). u32 lex keys.
__device__ __forceinline__ void merge2(unsigned &a1, unsigned &a2,
                                       unsigned b1, unsigned b2) {
    unsigned m1  = min(a1, b1);
    unsigned hi  = max(a1, b1);
    unsigned sel = (a1 < b1) ? a2 : b2;
    a2 = min(hi, sel);
    a1 = m1;
}

// ================= fused prep: e-convert+enorm  |  z-convert+zpart =================
// blocks [0,2048): per-code enorm (tree IDENTICAL to r1-10) + tiled-swizzled ET3
// blocks [2048,3072): z-section, LDS-transposed for FULL read coalescing:
//   stage 64 d x 64 s floats via contiguous float4 (256B/16-lane segments), then
//   per-(n,c2) 16-term sequential sums BYTE-IDENTICAL to r5-10 (same values,
//   same order — only the fetch path changed), zpart/ZT3 writes unchanged.

__global__ __launch_bounds__(256)
void prep_kernel(const float* __restrict__ emb, const float* __restrict__ z,
                 short* __restrict__ ET3, short* __restrict__ ZT3,
                 float* __restrict__ zpart, float* __restrict__ enorm,
                 float* __restrict__ enormB, float* __restrict__ out_loss) {
    __shared__ float tr[64][67];     // 16.75 KB, padded (e-blocks leave it unused)
    const int bx = blockIdx.x;
    const int t  = threadIdx.x;
    if (bx < 2048) {
        int k = bx * 4 + (t >> 6);
        int l = t & 63;
        float4 v = *(const float4*)(emb + (size_t)k * D_ + l * 4);
        float sum = v.x*v.x + v.y*v.y + v.z*v.z + v.w*v.w;
        for (int m = 1; m < 64; m <<= 1) sum += __shfl_xor(sum, m, 64);
        if (l == 0) { enorm[k] = sum; enormB[k] = sum + BIAS_; }
        int dcb  = l >> 4;
        int c    = (l >> 1) & 7;
        int half = l & 1;
        bf16x4 o;
        o[0] = (short)f2bf(v.x); o[1] = (short)f2bf(v.y);
        o[2] = (short)f2bf(v.z); o[3] = (short)f2bf(v.w);
        *(bf16x4*)(ET3 + ((size_t)dcb * K_ + k) * 64 + ((c ^ (k & 7)) * 8) + half * 4) = o;
    } else {
        int bz   = bx - 2048;                // 0..1023
        if (bz == 0 && t == 0) *out_loss = 0.f;
        int dcb  = bz & 3;
        int tile = bz >> 2;                  // 0..255, 64 rows each
        int n0   = tile * 64;
        int b    = n0 >> 10;
        int s0   = n0 & 1023;
        // stage: 64 d-rows x 16 float4 (coalesced 256B per 16 lanes)
#pragma unroll
        for (int i = 0; i < 4; ++i) {
            int p = t + i * 256;             // 0..1023
            int d = p >> 4;
            int q = p & 15;
            float4 v = *(const float4*)(z + (size_t)b * ZB
                                          + (size_t)(dcb * 64 + d) * SP + s0 + q * 4);
            tr[d][q*4+0] = v.x; tr[d][q*4+1] = v.y;
            tr[d][q*4+2] = v.z; tr[d][q*4+3] = v.w;
        }
        __syncthreads();
        int nl = t >> 2;                     // 0..63
        int c2 = t & 3;
        int n  = n0 + nl;
        int sw = n & 7;
        short* dst = ZT3 + ((size_t)dcb * N_TOT + n) * 64;
        float vv[16];
#pragma unroll
        for (int dd = 0; dd < 16; ++dd)
            vv[dd] = tr[c2 * 16 + dd][nl];
        float sum = 0.f;
#pragma unroll
        for (int dd = 0; dd < 16; ++dd) {
            float v = vv[dd];
            sum += v * v;
        }
        zpart[(size_t)(dcb * 4 + c2) * N_TOT + n] = sum;
        bf16x8 o0, o1;
#pragma unroll
        for (int j = 0; j < 8; ++j) { o0[j] = (short)f2bf(vv[j]);
                                      o1[j] = (short)f2bf(vv[8 + j]); }
        *(bf16x8*)(dst + (((c2 * 2)     ^ sw) * 8)) = o0;
        *(bf16x8*)(dst + (((c2 * 2 + 1) ^ sw) * 8)) = o1;
    }
}

// ============== MFMA GEMM + packed-key top-2 (round-5/8/9/10 proven, byte-identical) ==============

__global__ __launch_bounds__(256, 4)
void mfma_argmin2(const short* __restrict__ ET3, const short* __restrict__ ZT3,
                  const float* __restrict__ enormB, uint2* __restrict__ pv) {
    __shared__ char smem[32768];
    const int t    = threadIdx.x;
    const int wid  = t >> 6, lane = t & 63;
    const int quad = lane >> 4, l16 = lane & 15;
    const int wm   = wid >> 1, wn = wid & 1;
    const int stripe = blockIdx.x >> 7;
    const int n0     = (blockIdx.x & 127) * 128;
    const int swz    = (l16 & 7);

    unsigned r1[4], r2[4];
#pragma unroll
    for (int fj = 0; fj < 4; ++fj) { r1[fj] = 0xFFFFFFFFu; r2[fj] = 0xFFFFFFFFu; }

#pragma unroll 1
    for (int cc = 0; cc < 8; ++cc) {
        const int c0 = stripe * 1024 + cc * 128;
        f32x4 acc[4][4];
#pragma unroll
        for (int fi = 0; fi < 4; ++fi)
#pragma unroll
            for (int fj = 0; fj < 4; ++fj) acc[fi][fj] = (f32x4){0.f, 0.f, 0.f, 0.f};

#pragma unroll 1
        for (int dcb = 0; dcb < 4; ++dcb) {
            __syncthreads();
            const char* gA = (const char*)ET3 + ((size_t)dcb * K_    + c0) * 128;
            const char* gB = (const char*)ZT3 + ((size_t)dcb * N_TOT + n0) * 128;
#pragma unroll
            for (int j = 0; j < 4; ++j) {
                int off = j * 4096 + t * 16;
                GLOAD_LDS16(gA + off, smem + off);
                GLOAD_LDS16(gB + off, smem + 16384 + off);
            }
            __syncthreads();
#pragma unroll
            for (int dc2 = 0; dc2 < 2; ++dc2) {
                bf16x8 af[4], bfv[4];
                const int chm = ((dc2 * 4 + quad) ^ swz) * 16;
#pragma unroll
                for (int fi = 0; fi < 4; ++fi)
                    af[fi] = *(const bf16x8*)(smem + (wm*64 + fi*16 + l16)*128 + chm);
#pragma unroll
                for (int fj = 0; fj < 4; ++fj)
                    bfv[fj] = *(const bf16x8*)(smem + 16384 + (wn*64 + fj*16 + l16)*128 + chm);
#pragma unroll
                for (int fi = 0; fi < 4; ++fi)
#pragma unroll
                    for (int fj = 0; fj < 4; ++fj)
                        acc[fi][fj] = __builtin_amdgcn_mfma_f32_16x16x32_bf16(
                            af[fi], bfv[fj], acc[fi][fj], 0, 0, 0);
            }
        }

        float ekv[4][4];
#pragma unroll
        for (int fi = 0; fi < 4; ++fi) {
            float4 e4 = *(const float4*)(enormB + c0 + wm*64 + fi*16 + quad*4);
            ekv[fi][0]=e4.x; ekv[fi][1]=e4.y; ekv[fi][2]=e4.z; ekv[fi][3]=e4.w;
        }
#pragma unroll
        for (int fj = 0; fj < 4; ++fj) {
#pragma unroll
            for (int fi = 0; fi < 4; ++fi) {
                const unsigned cb = (unsigned)(c0 + wm*64 + fi*16 + quad*4);
                float s0 = fmaf(-2.f, acc[fi][fj].x, ekv[fi][0]);
                float s1 = fmaf(-2.f, acc[fi][fj].y, ekv[fi][1]);
                float s2 = fmaf(-2.f, acc[fi][fj].z, ekv[fi][2]);
                float s3 = fmaf(-2.f, acc[fi][fj].w, ekv[fi][3]);
                unsigned k0 = (__float_as_uint(s0) & 0xFFFFE000u) | (cb + 0u);
                unsigned k1 = (__float_as_uint(s1) & 0xFFFFE000u) | (cb + 1u);
                unsigned k2 = (__float_as_uint(s2) & 0xFFFFE000u) | (cb + 2u);
                unsigned k3 = (__float_as_uint(s3) & 0xFFFFE000u) | (cb + 3u);
                unsigned lo1 = min(k0, k1), hi1 = max(k0, k1);
                unsigned lo2 = min(k2, k3), hi2 = max(k2, k3);
                merge2(lo1, hi1, lo2, hi2);
                merge2(r1[fj], r2[fj], lo1, hi1);
            }
        }
    }

#pragma unroll
    for (int fj = 0; fj < 4; ++fj) {
        unsigned a1 = r1[fj], a2 = r2[fj];
#pragma unroll
        for (int m = 16; m <= 32; m <<= 1) {
            unsigned b1 = __shfl_xor(a1, m, 64);
            unsigned b2 = __shfl_xor(a2, m, 64);
            merge2(a1, a2, b1, b2);
        }
        if (quad == 0) {
            int n = n0 + wn*64 + fj*16 + l16;
            pv[(size_t)(stripe * 2 + wm) * N_TOT + n] = make_uint2(a1, a2);
        }
    }
}

// ============== fused tail: classify + block-local recheck + output + loss ==============
// 512 blocks x 32 rows (round-10 proven, byte-identical).

__global__ __launch_bounds__(256)
void tail_fused(const uint2* __restrict__ pv, const float* __restrict__ zpart,
                const float* __restrict__ enorm, const float* __restrict__ z,
                const float* __restrict__ emb, float* __restrict__ out,
                float* __restrict__ out_idx, float* __restrict__ loss) {
    __shared__ float eL[32][257];     // 32.9 KB: emb rows for the 32 n's
    __shared__ float zrow[4][256];    // per-wave recheck z-row slots
    __shared__ int   fid[32];
    __shared__ int   wlL[32];
    __shared__ int   nflag;
    __shared__ float red[4];

    const int t  = threadIdx.x;
    const int n0 = blockIdx.x * 32;
    const int b  = n0 >> 10;
    const int s0 = n0 & 1023;

    if (t == 0) nflag = 0;
    __syncthreads();

    // ---- phase 1: classify 32 rows (identical window expressions) ----
    if (t < 32) {
        int n = n0 + t;
        uint2 pp[16];
        unsigned mn = 0xFFFFFFFFu;
#pragma unroll
        for (int g = 0; g < 16; ++g) {
            pp[g] = pv[(size_t)g * N_TOT + n];
            mn = min(mn, pp[g].x);
        }
        float smin  = __uint_as_float(mn & 0xFFFFE000u);
        unsigned th = __float_as_uint(smin + DELTA_) | 8191u;
        int cnt = 0;
#pragma unroll
        for (int g = 0; g < 16; ++g) {
            cnt += (pp[g].x <= th) ? 1 : 0;
            cnt += (pp[g].y <= th) ? 1 : 0;
        }
        if (cnt > 1) {
            int slot = atomicAdd(&nflag, 1);
            wlL[slot] = t;
        } else {
            int c = (int)(mn & 8191u);
            fid[t] = c;
            out_idx[n] = (float)c;
        }
    }
    __syncthreads();

    // ---- phase 2: block-local recheck, one wave per flagged row ----
    const int lane = t & 63;
    const int wid  = t >> 6;
    const int nf   = nflag;
    for (int i = wid; i < nf; i += 4) {
        int r = wlL[i];
        int n = n0 + r;
        unsigned key = 0xFFFFFFFFu;
        if (lane < 32) {
            uint2 p = pv[(size_t)(lane >> 1) * N_TOT + n];
            key = (lane & 1) ? p.y : p.x;
        }
        unsigned mn = key;
#pragma unroll
        for (int m = 1; m < 64; m <<= 1) mn = min(mn, __shfl_xor(mn, m, 64));
        float smin  = __uint_as_float(mn & 0xFFFFE000u);
        unsigned th = __float_as_uint(smin + DELTA_) | 8191u;

        // zn: bit-identical sequential 16-term sum over zpart (znorm's tree)
        float zp = 0.f;
        if (lane < 16) zp = zpart[(size_t)lane * N_TOT + n];
        float zn = 0.f;
#pragma unroll
        for (int dc = 0; dc < 16; ++dc) zn += __shfl(zp, dc, 64);

        const float* zr = z + (size_t)b * ZB + (s0 + r);
#pragma unroll
        for (int j = 0; j < 4; ++j)
            zrow[wid][lane + j * 64] = zr[(size_t)(lane + j * 64) * SP];

        unsigned lexlo = 0xFFFFFFFFu, lexhi = 0xFFFFFFFFu;
        if (key <= th) {
            int c = (int)(key & 8191u);
            const float* er = emb + (size_t)c * D_;
            float dot = 0.f;
#pragma unroll 8
            for (int d = 0; d < D_; ++d)
                dot = fmaf(zrow[wid][d], er[d], dot);
            float s = (zn + enorm[c]) - 2.f * dot;
            unsigned sb = __float_as_uint(s);
            lexhi = sb >> 19;
            lexlo = (sb << 13) | (unsigned)c;
        }
#pragma unroll
        for (int m = 1; m < 64; m <<= 1) {
            unsigned olo = __shfl_xor(lexlo, m, 64);
            unsigned ohi = __shfl_xor(lexhi, m, 64);
            if (ohi < lexhi || (ohi == lexhi && olo < lexlo)) { lexhi = ohi; lexlo = olo; }
        }
        if (lane == 0) {
            int c = (int)(lexlo & 8191u);
            fid[r] = c;
            out_idx[n] = (float)c;
        }
    }
    __syncthreads();

    // ---- phase 3: stage the 32 selected emb rows into LDS ----
#pragma unroll
    for (int i = 0; i < 8; ++i) {
        int p = t + i * 256;             // 2048 float4 slots: row = p>>6, q = p&63
        int row = p >> 6, q = p & 63;
        float4 v = *(const float4*)(emb + (size_t)fid[row] * D_ + q * 4);
        eL[row][q*4+0] = v.x; eL[row][q*4+1] = v.y;
        eL[row][q*4+2] = v.z; eL[row][q*4+3] = v.w;
    }
    __syncthreads();

    // ---- phase 4: stream out + loss (float4 over spatial) ----
    const int sq = t & 7, dg = t >> 3;   // 8 float4-spans x 32 d-groups
    float lsum = 0.f;
#pragma unroll
    for (int i = 0; i < 8; ++i) {
        int d = dg * 8 + i;
        size_t off = ((size_t)(b * D_ + d)) * SP + s0 + sq * 4;
        float4 z4 = *(const float4*)(z + off);
        float q0 = eL[sq*4+0][d], q1 = eL[sq*4+1][d];
        float q2 = eL[sq*4+2][d], q3 = eL[sq*4+3][d];
        float d0 = q0 - z4.x, d1 = q1 - z4.y;     // fl(q - z)
        float d2 = q2 - z4.z, d3 = q3 - z4.w;
        float4 o4 = make_float4(z4.x + d0, z4.y + d1,   // fl(z + fl(q-z))
                                z4.z + d2, z4.w + d3);
        *(float4*)(out + off) = o4;
        lsum += d0*d0; lsum += d1*d1; lsum += d2*d2; lsum += d3*d3;
    }
    for (int m = 1; m < 64; m <<= 1) lsum += __shfl_xor(lsum, m, 64);
    if ((t & 63) == 0) red[t >> 6] = lsum;
    __syncthreads();
    if (t == 0) {
        float tot = (red[0] + red[1] + red[2] + red[3])
                    * (1.25f / (float)(B_ * SP * D_));
        atomicAdd(loss, tot);
    }
}

// ======================= launch =======================
// ws layout (floats) — NEED = 15,794,176 B (< proven grant):
//   enorm [0,8192)  enormB [8192,16384)  zpart [16384,278528)
//   pv16 [278528,802816)
//   ET3 (short) [802816,1851392)   ZT3 (short) [1851392,3948544)

extern "C" void kernel_launch(void* const* d_in, const int* in_sizes, int n_in,
                              void* d_out, int out_size, void* d_ws, size_t ws_size,
                              hipStream_t stream) {
    const float* z   = (const float*)d_in[0];
    const float* emb = (const float*)d_in[1];
    float* out = (float*)d_out;
    float* w   = (float*)d_ws;

    float* enorm  = w;
    float* enormB = w + 8192;
    float* zpart  = w + 16384;
    uint2* pv     = (uint2*)(w + 278528);
    short* ET3    = (short*)(w + 802816);
    short* ZT3    = (short*)(w + 1851392);

    float* out0     = out;
    float* out_loss = out + (size_t)B_ * D_ * SP;
    float* out_idx  = out_loss + 1;

    prep_kernel<<<3072, 256, 0, stream>>>(emb, z, ET3, ZT3, zpart,
                                          enorm, enormB, out_loss);
    mfma_argmin2<<<1024, 256, 0, stream>>>(ET3, ZT3, enormB, pv);
    tail_fused<<<512, 256, 0, stream>>>(pv, zpart, enorm, z, emb,
                                        out0, out_idx, out_loss);
}